// Round 5
// baseline (111.348 us; speedup 1.0000x reference)
//
#include <hip/hip_runtime.h>

// WeightedPairwiseLoss: B=32, N=4096, k=819 (= int(0.2*4096)), 4 f32 scalar outputs.
#define B 32
#define N 4096
#define K 819
#define KP 832                 // padded row stride; KP = JC2*JL2 exactly
#define SBASE (4*B*KP)         // scalar section start (float index)
#define JC2 32                 // j-chunks in pairwise kernel
#define JL2 26                 // j per chunk (32*26 = 832)
// ws layout:
//  float2 [0      , B*KP)   : top (score, sqrtw), row stride KP, pads w=0
//  float2 [B*KP   , 2*B*KP) : bot (score, sqrtw)
//  float scalars at SBASE + slot*B + r:
//   slot 0: sumTopSqw (atomic)   slot 1: sumBotSqw (atomic)
//   slot 2: bceNum    (atomic)   slot 3: wmSum     (atomic)
//   slot 4: pMaskSum  (atomic)   slot 5: maskSum   (atomic)
//   slot 6: rankNum   (atomic)   slot 7: t_lo      slot 8: t_hi
//   slot 9: cntTop (int, atomic) slot 10: cntBot (int, atomic)
//   SBASE + 11*B : doneCnt (single int)
#define S_SLOT(s, r) (SBASE + (s)*B + (r))

// One wave: find bucket containing 0-based rank R in hist[0..2048); bucket
// walk happens in registers. Exactly one lane writes the outputs.
__device__ __forceinline__ void select_bucket(const int* hist, int R,
                                              int* outBkt, int* outRem) {
  const int lane = threadIdx.x & 63;
  int cnt[32];
  int s = 0;
#pragma unroll
  for (int q = 0; q < 32; q++) { cnt[q] = hist[lane * 32 + q]; s += cnt[q]; }
  int inc = s;
#pragma unroll
  for (int off = 1; off < 64; off <<= 1) {
    int v = __shfl_up(inc, off);
    if (lane >= off) inc += v;
  }
  int exc = inc - s;
  if (R >= exc && R < exc + s) {
    int rem = R - exc, b = 0;
#pragma unroll
    for (int q = 0; q < 32; q++)
      if (b == q && rem >= cnt[q]) { rem -= cnt[q]; b = q + 1; }
    *outBkt = lane * 32 + b;
    *outRem = rem;
  }
}

// One wave: pick the rem-th smallest of cand[0..c) (c <= 64); winner writes *out.
__device__ __forceinline__ void pick_kth(const float* cand, int c, int rem,
                                         float* out) {
  const int lane = threadIdx.x & 63;
  float v = (lane < c) ? cand[lane] : 3.4e38f;
  int rk = 0;
#pragma unroll 8
  for (int m = 0; m < 64; m++) {
    float u = __shfl(v, m);
    rk += (u < v || (u == v && m < lane)) ? 1 : 0;
  }
  if (lane < c && rk == rem) *out = v;
}

// Kernel 1: per-row exact rank thresholds of y_rank (one 2048-bucket linear
// histogram + tiny candidate set). Also zero-inits all global accumulators
// and the pair-array pads. Reads ONLY y_rank (512 KB).
__global__ __launch_bounds__(1024) void wpl_thresh(
    const float* __restrict__ y_rank, float* __restrict__ ws) {
  const int r = blockIdx.x;
  const int tid = threadIdx.x;
  __shared__ int hist[2048];
  __shared__ float redMn[16], redMx[16];
  __shared__ float sMn, sScale, sTlo, sThi;
  __shared__ float candA[64], candB[64];
  __shared__ int cA, cB, bktA, remA, bktB, remB;

  const float4 y4 = ((const float4*)(y_rank + r * N))[tid];
  const float yv[4] = {y4.x, y4.y, y4.z, y4.w};

  // zero global accumulators (slots 0..6, 9, 10) + doneCnt + pads
  if (tid < 7) ws[S_SLOT(tid, r)] = 0.0f;
  else if (tid < 9) ws[S_SLOT(tid + 2, r)] = 0.0f;      // slots 9,10 (ints, 0 bits)
  else if (r == 0 && tid == 9) ((int*)ws)[SBASE + 11 * B] = 0;
  {
    float2* top = (float2*)ws + (size_t)r * KP;
    float2* bot = (float2*)ws + (size_t)(B + r) * KP;
    if (tid < KP - K) {
      top[K + tid] = make_float2(0.0f, 0.0f);
      bot[K + tid] = make_float2(0.0f, 0.0f);
    }
  }

  hist[tid] = 0; hist[tid + 1024] = 0;
  if (tid == 0) { cA = 0; cB = 0; }
  float mn = fminf(fminf(yv[0], yv[1]), fminf(yv[2], yv[3]));
  float mx = fmaxf(fmaxf(yv[0], yv[1]), fmaxf(yv[2], yv[3]));
#pragma unroll
  for (int off = 32; off > 0; off >>= 1) {
    mn = fminf(mn, __shfl_down(mn, off));
    mx = fmaxf(mx, __shfl_down(mx, off));
  }
  if ((tid & 63) == 0) { redMn[tid >> 6] = mn; redMx[tid >> 6] = mx; }
  __syncthreads();
  if (tid == 0) {
    float a = redMn[0], b = redMx[0];
    for (int q = 1; q < 16; q++) { a = fminf(a, redMn[q]); b = fmaxf(b, redMx[q]); }
    sMn = a;
    sScale = 2048.0f / (b - a + 1e-20f);
  }
  __syncthreads();

  const float bmn = sMn, bsc = sScale;
#pragma unroll
  for (int q = 0; q < 4; q++) {
    int bkt = (int)((yv[q] - bmn) * bsc);
    atomicAdd(&hist[min(2047, max(0, bkt))], 1);
  }
  __syncthreads();

  if (tid < 64)       select_bucket(hist, K - 1, &bktA, &remA);   // t_lo
  else if (tid < 128) select_bucket(hist, N - K, &bktB, &remB);   // t_hi
  __syncthreads();

  {
    const int bA = bktA, bB = bktB;
#pragma unroll
    for (int q = 0; q < 4; q++) {
      int bkt = (int)((yv[q] - bmn) * bsc);
      bkt = min(2047, max(0, bkt));
      if (bkt == bA) { int p = atomicAdd(&cA, 1); if (p < 64) candA[p] = yv[q]; }
      if (bkt == bB) { int p = atomicAdd(&cB, 1); if (p < 64) candB[p] = yv[q]; }
    }
  }
  __syncthreads();

  if (tid < 64)       pick_kth(candA, cA, remA, &sTlo);
  else if (tid < 128) pick_kth(candB, cB, remB, &sThi);
  __syncthreads();
  if (tid == 0) { ws[S_SLOT(7, r)] = sTlo; ws[S_SLOT(8, r)] = sThi; }
}

// Kernel 2: full-chip compaction + O(N) row reductions. 8 chunks/row x 32 rows
// = 256 blocks x 128 threads; float4 per thread. Global atomics for positions
// (compiler wave-aggregates) and float atomics for the 6 row accumulators.
__global__ __launch_bounds__(128) void wpl_reduce(
    const float* __restrict__ scores, const float* __restrict__ p_trade,
    const float* __restrict__ y_rank, const float* __restrict__ y_trade,
    const float* __restrict__ weights, const unsigned char* __restrict__ mask,
    float* __restrict__ ws) {
  const int chunk = blockIdx.x;
  const int r = blockIdx.y;
  const int tid = threadIdx.x;
  const int e0 = chunk * 512 + tid * 4;        // element index within row
  const size_t base = (size_t)r * N + e0;
  __shared__ float red[2 * 6];

  const float4 y4 = *(const float4*)(y_rank  + base);
  const float4 s4 = *(const float4*)(scores  + base);
  const float4 w4 = *(const float4*)(weights + base);
  const float4 p4 = *(const float4*)(p_trade + base);
  const float4 t4 = *(const float4*)(y_trade + base);
  const uchar4 m4 = *(const uchar4*)(mask + base);
  const float yv[4] = {y4.x, y4.y, y4.z, y4.w};
  const float sv[4] = {s4.x, s4.y, s4.z, s4.w};
  const float wv[4] = {w4.x, w4.y, w4.z, w4.w};
  const float pv[4] = {p4.x, p4.y, p4.z, p4.w};
  const float tv[4] = {t4.x, t4.y, t4.z, t4.w};
  const unsigned char mv[4] = {m4.x, m4.y, m4.z, m4.w};

  const float t_lo = ws[S_SLOT(7, r)];
  const float t_hi = ws[S_SLOT(8, r)];
  int* cntTop = (int*)ws + S_SLOT(9, r);
  int* cntBot = (int*)ws + S_SLOT(10, r);
  float2* top = (float2*)ws + (size_t)r * KP;
  float2* bot = (float2*)ws + (size_t)(B + r) * KP;

  float a0 = 0, a1 = 0, a2 = 0, a3 = 0, a4 = 0, a5 = 0;
#pragma unroll
  for (int q = 0; q < 4; q++) {
    float w  = wv[q];
    float sq = sqrtf(w);
    if (yv[q] >= t_hi) {
      int pos = atomicAdd(cntTop, 1);
      if (pos < K) { top[pos] = make_float2(sv[q], sq); a0 += sq; }
    }
    if (yv[q] <= t_lo) {
      int pos = atomicAdd(cntBot, 1);
      if (pos < K) { bot[pos] = make_float2(sv[q], sq); a1 += sq; }
    }
    float p  = pv[q];
    float m  = mv[q] ? 1.0f : 0.0f;
    float lp = fmaxf(__logf(p), -100.0f);
    float l1 = fmaxf(log1pf(-p), -100.0f);
    float bce = -(tv[q] * lp + (1.0f - tv[q]) * l1);
    float wm = w * m;
    a2 += bce * wm;
    a3 += wm;
    a4 += p * m;
    a5 += m;
  }

  float vals[6] = {a0, a1, a2, a3, a4, a5};
#pragma unroll
  for (int q = 0; q < 6; q++)
#pragma unroll
    for (int off = 32; off > 0; off >>= 1)
      vals[q] += __shfl_down(vals[q], off);
  if ((tid & 63) == 0) {
#pragma unroll
    for (int q = 0; q < 6; q++) red[(tid >> 6) * 6 + q] = vals[q];
  }
  __syncthreads();
  if (tid < 6) atomicAdd(&ws[S_SLOT(tid, r)], red[tid] + red[6 + tid]);
}

// Kernel 3: pairwise numerator + (in the last-finished block) final combine.
// rankNum_r = sum_i sqw_i * sum_j softplus(bot_j - top_i) * sqw_j.
// Grid (JC2, B) = 1024 blocks x 256 threads; 4 i per thread, 26 j in LDS.
__global__ __launch_bounds__(256) void wpl_pair(float* __restrict__ ws,
                                                float* __restrict__ out) {
  const int cj = blockIdx.x;
  const int r  = blockIdx.y;
  const int tid = threadIdx.x;
  __shared__ float2 bsw[JL2];
  __shared__ float red[4];
  __shared__ int isLast;
  const float2* top = (const float2*)ws + (size_t)r * KP;
  const float2* bot = (const float2*)ws + (size_t)(B + r) * KP;
  if (tid < JL2) bsw[tid] = bot[cj * JL2 + tid];
  __syncthreads();

  float acc = 0.0f;
#pragma unroll
  for (int q = 0; q < 4; q++) {
    const int i = q * 256 + tid;
    float2 sw = (i < KP) ? top[i] : make_float2(0.0f, 0.0f);
    float a = 0.0f;
#pragma unroll
    for (int j = 0; j < JL2; j++) {
      float z  = bsw[j].x - sw.x;                              // s_bot - s_top
      float sp = fmaxf(z, 0.0f) + __logf(1.0f + __expf(-fabsf(z)));
      a += sp * bsw[j].y;
    }
    acc += a * sw.y;
  }
#pragma unroll
  for (int off = 32; off > 0; off >>= 1) acc += __shfl_down(acc, off);
  if ((tid & 63) == 0) red[tid >> 6] = acc;
  __syncthreads();
  if (tid == 0) {
    atomicAdd(&ws[S_SLOT(6, r)], red[0] + red[1] + red[2] + red[3]);
    __threadfence();
    int ticket = atomicAdd((int*)ws + SBASE + 11 * B, 1);
    isLast = (ticket == JC2 * B - 1) ? 1 : 0;
  }
  __syncthreads();

  if (isLast) {
    __threadfence();
    float lr = 0, lt = 0, ps = 0, ms = 0;
    if (tid < B) {
      float num = ws[S_SLOT(6, tid)];
      float den = ws[S_SLOT(0, tid)] * ws[S_SLOT(1, tid)] + 1e-8f;
      lr = num / den;
      lt = ws[S_SLOT(2, tid)] / (ws[S_SLOT(3, tid)] + 1e-8f);
      ps = ws[S_SLOT(4, tid)];
      ms = ws[S_SLOT(5, tid)];
    }
#pragma unroll
    for (int off = 16; off > 0; off >>= 1) {
      lr += __shfl_down(lr, off);
      lt += __shfl_down(lt, off);
      ps += __shfl_down(ps, off);
      ms += __shfl_down(ms, off);
    }
    if (tid == 0) {
      float avg_rank  = lr * (1.0f / B);
      float avg_trade = lt * (1.0f / B);
      out[0] = avg_rank + 0.25f * avg_trade;
      out[1] = avg_rank;
      out[2] = avg_trade;
      out[3] = ps / ms;
    }
  }
}

extern "C" void kernel_launch(void* const* d_in, const int* in_sizes, int n_in,
                              void* d_out, int out_size, void* d_ws, size_t ws_size,
                              hipStream_t stream) {
  const float* scores  = (const float*)d_in[0];
  const float* p_trade = (const float*)d_in[1];
  const float* y_rank  = (const float*)d_in[2];
  const float* y_trade = (const float*)d_in[3];
  const float* weights = (const float*)d_in[4];
  const unsigned char* mask = (const unsigned char*)d_in[5];
  float* out = (float*)d_out;
  float* ws  = (float*)d_ws;

  wpl_thresh<<<B, 1024, 0, stream>>>(y_rank, ws);
  wpl_reduce<<<dim3(8, B), 128, 0, stream>>>(scores, p_trade, y_rank, y_trade,
                                             weights, mask, ws);
  wpl_pair<<<dim3(JC2, B), 256, 0, stream>>>(ws, out);
}

// Round 6
// 101.524 us; speedup vs baseline: 1.0968x; 1.0968x over previous
//
#include <hip/hip_runtime.h>

// WeightedPairwiseLoss: B=32, N=4096, k=819 (= int(0.2*4096)), 4 f32 scalar outputs.
#define B 32
#define N 4096
#define K 819
#define KP 832                 // padded row stride; KP = JC2*JL2 exactly
#define SBASE (4*B*KP)         // scalar section start (float index)
#define JC2 32                 // j-chunks in pairwise kernel
#define JL2 26                 // j per chunk (32*26 = 832)
// ws layout:
//  float2 [0      , B*KP)   : top (score, sqrtw), row stride KP, pads w=0
//  float2 [B*KP   , 2*B*KP) : bot (score, sqrtw)
//  float scalars at SBASE + slot*B + r:
//   slot 0: sumTopSqw  slot 1: sumBotSqw  slot 2: bceNum  slot 3: wmSum
//   slot 4: pMaskSum   slot 5: maskSum    slot 6: rankNum (atomic)
//   SBASE + 7*B : doneCnt (single int)
#define S_SLOT(s, r) (SBASE + (s)*B + (r))

// One wave: find bucket containing 0-based rank R in hist[0..2048); bucket
// walk happens in registers. Exactly one lane writes the outputs.
__device__ __forceinline__ void select_bucket(const int* hist, int R,
                                              int* outBkt, int* outRem) {
  const int lane = threadIdx.x & 63;
  int cnt[32];
  int s = 0;
#pragma unroll
  for (int q = 0; q < 32; q++) { cnt[q] = hist[lane * 32 + q]; s += cnt[q]; }
  int inc = s;
#pragma unroll
  for (int off = 1; off < 64; off <<= 1) {
    int v = __shfl_up(inc, off);
    if (lane >= off) inc += v;
  }
  int exc = inc - s;
  if (R >= exc && R < exc + s) {
    int rem = R - exc, b = 0;
#pragma unroll
    for (int q = 0; q < 32; q++)
      if (b == q && rem >= cnt[q]) { rem -= cnt[q]; b = q + 1; }
    *outBkt = lane * 32 + b;
    *outRem = rem;
  }
}

// One wave: pick the rem-th smallest of cand[0..c) (c <= 64); winner writes *out.
__device__ __forceinline__ void pick_kth(const float* cand, int c, int rem,
                                         float* out) {
  const int lane = threadIdx.x & 63;
  float v = (lane < c) ? cand[lane] : 3.4e38f;
  int rk = 0;
#pragma unroll 8
  for (int m = 0; m < 64; m++) {
    float u = __shfl(v, m);
    rk += (u < v || (u == v && m < lane)) ? 1 : 0;
  }
  if (lane < c && rk == rem) *out = v;
}

// Phase 1 (monolithic, 1 block/row): exact rank thresholds of y_rank via one
// value-linear 2048-bucket histogram + tiny candidate set; LDS-counter
// compaction of top/bot (score, sqrtw); all O(N) row reductions. Also inits
// rankNum accumulator + doneCnt for the fused combine in phase 2.
__global__ __launch_bounds__(1024) void wpl_phase1(
    const float* __restrict__ scores, const float* __restrict__ p_trade,
    const float* __restrict__ y_rank, const float* __restrict__ y_trade,
    const float* __restrict__ weights, const unsigned char* __restrict__ mask,
    float* __restrict__ ws) {
  const int r = blockIdx.x;
  const int tid = threadIdx.x;
  __shared__ int hist[2048];
  __shared__ float redMn[16], redMx[16];
  __shared__ float red[16 * 6];
  __shared__ float sMn, sScale, sTlo, sThi;
  __shared__ float candA[64], candB[64];
  __shared__ int cA, cB, cntTop, cntBot;
  __shared__ int bktA, remA, bktB, remB;

  // ---- load row into registers (vectorized) ----
  const float4 y4 = ((const float4*)(y_rank  + r * N))[tid];
  const float4 s4 = ((const float4*)(scores  + r * N))[tid];
  const float4 w4 = ((const float4*)(weights + r * N))[tid];
  const float4 p4 = ((const float4*)(p_trade + r * N))[tid];
  const float4 t4 = ((const float4*)(y_trade + r * N))[tid];
  const uchar4 m4 = ((const uchar4*)(mask    + r * N))[tid];
  const float yv[4] = {y4.x, y4.y, y4.z, y4.w};
  const float sv[4] = {s4.x, s4.y, s4.z, s4.w};
  const float wv[4] = {w4.x, w4.y, w4.z, w4.w};
  const float pv[4] = {p4.x, p4.y, p4.z, p4.w};
  const float tv[4] = {t4.x, t4.y, t4.z, t4.w};
  const unsigned char mv[4] = {m4.x, m4.y, m4.z, m4.w};

  // ---- init: hist, global accumulators for phase2, pads ----
  hist[tid] = 0; hist[tid + 1024] = 0;
  if (tid == 0) { cA = 0; cB = 0; cntTop = 0; cntBot = 0; }
  if (tid == 1) ws[S_SLOT(6, r)] = 0.0f;                    // rankNum
  if (r == 0 && tid == 2) ((int*)ws)[SBASE + 7 * B] = 0;    // doneCnt
  {
    float2* top = (float2*)ws + (size_t)r * KP;
    float2* bot = (float2*)ws + (size_t)(B + r) * KP;
    if (tid < KP - K) {
      top[K + tid] = make_float2(0.0f, 0.0f);
      bot[K + tid] = make_float2(0.0f, 0.0f);
    }
  }
  float mn = fminf(fminf(yv[0], yv[1]), fminf(yv[2], yv[3]));
  float mx = fmaxf(fmaxf(yv[0], yv[1]), fmaxf(yv[2], yv[3]));
#pragma unroll
  for (int off = 32; off > 0; off >>= 1) {
    mn = fminf(mn, __shfl_down(mn, off));
    mx = fmaxf(mx, __shfl_down(mx, off));
  }
  if ((tid & 63) == 0) { redMn[tid >> 6] = mn; redMx[tid >> 6] = mx; }
  __syncthreads();
  if (tid == 0) {
    float a = redMn[0], b = redMx[0];
    for (int q = 1; q < 16; q++) { a = fminf(a, redMn[q]); b = fmaxf(b, redMx[q]); }
    sMn = a;
    sScale = 2048.0f / (b - a + 1e-20f);
  }
  __syncthreads();

  // ---- linear histogram ----
  const float bmn = sMn, bsc = sScale;
#pragma unroll
  for (int q = 0; q < 4; q++) {
    int bkt = (int)((yv[q] - bmn) * bsc);
    atomicAdd(&hist[min(2047, max(0, bkt))], 1);
  }
  __syncthreads();

  // ---- find rank buckets (two waves in parallel) ----
  if (tid < 64)       select_bucket(hist, K - 1, &bktA, &remA);   // t_lo
  else if (tid < 128) select_bucket(hist, N - K, &bktB, &remB);   // t_hi
  __syncthreads();

  // ---- gather candidates from the two rank buckets ----
  {
    const int bA = bktA, bB = bktB;
#pragma unroll
    for (int q = 0; q < 4; q++) {
      int bkt = (int)((yv[q] - bmn) * bsc);
      bkt = min(2047, max(0, bkt));
      if (bkt == bA) { int p = atomicAdd(&cA, 1); if (p < 64) candA[p] = yv[q]; }
      if (bkt == bB) { int p = atomicAdd(&cB, 1); if (p < 64) candB[p] = yv[q]; }
    }
  }
  __syncthreads();

  // ---- exact thresholds ----
  if (tid < 64)       pick_kth(candA, cA, remA, &sTlo);
  else if (tid < 128) pick_kth(candB, cB, remB, &sThi);
  __syncthreads();
  const float t_lo = sTlo, t_hi = sThi;

  // ---- compaction (LDS counters) + O(N) reductions ----
  float2* top = (float2*)ws + (size_t)r * KP;
  float2* bot = (float2*)ws + (size_t)(B + r) * KP;

  float a0 = 0, a1 = 0, a2 = 0, a3 = 0, a4 = 0, a5 = 0;
#pragma unroll
  for (int q = 0; q < 4; q++) {
    float w  = wv[q];
    float sq = sqrtf(w);
    if (yv[q] >= t_hi) {                   // top set (cap K for ties)
      int pos = atomicAdd(&cntTop, 1);
      if (pos < K) { top[pos] = make_float2(sv[q], sq); a0 += sq; }
    }
    if (yv[q] <= t_lo) {                   // bot set
      int pos = atomicAdd(&cntBot, 1);
      if (pos < K) { bot[pos] = make_float2(sv[q], sq); a1 += sq; }
    }
    float p  = pv[q];
    float m  = mv[q] ? 1.0f : 0.0f;
    float lp = fmaxf(__logf(p), -100.0f);
    float l1 = fmaxf(log1pf(-p), -100.0f);
    float bce = -(tv[q] * lp + (1.0f - tv[q]) * l1);
    float wm = w * m;
    a2 += bce * wm;
    a3 += wm;
    a4 += p * m;
    a5 += m;
  }

  float vals[6] = {a0, a1, a2, a3, a4, a5};
#pragma unroll
  for (int q = 0; q < 6; q++)
#pragma unroll
    for (int off = 32; off > 0; off >>= 1)
      vals[q] += __shfl_down(vals[q], off);
  const int wave = tid >> 6;
  if ((tid & 63) == 0) {
#pragma unroll
    for (int q = 0; q < 6; q++) red[wave * 6 + q] = vals[q];
  }
  __syncthreads();
  if (tid < 6) {
    float t = 0;
    for (int w2 = 0; w2 < 16; w2++) t += red[w2 * 6 + tid];
    ws[S_SLOT(tid, r)] = t;
  }
}

// Phase 2: pairwise numerator + fused final combine in the last block.
// rankNum_r = sum_i sqw_i * sum_j softplus(bot_j - top_i) * sqw_j.
// Grid (JC2, B) = 1024 blocks x 256 threads; 4 i per thread, 26 j in LDS.
__global__ __launch_bounds__(256) void wpl_pair(float* __restrict__ ws,
                                                float* __restrict__ out) {
  const int cj = blockIdx.x;
  const int r  = blockIdx.y;
  const int tid = threadIdx.x;
  __shared__ float2 bsw[JL2];
  __shared__ float red[4];
  __shared__ int isLast;
  const float2* top = (const float2*)ws + (size_t)r * KP;
  const float2* bot = (const float2*)ws + (size_t)(B + r) * KP;
  if (tid < JL2) bsw[tid] = bot[cj * JL2 + tid];
  __syncthreads();

  float acc = 0.0f;
#pragma unroll
  for (int q = 0; q < 4; q++) {
    const int i = q * 256 + tid;
    float2 sw = (i < KP) ? top[i] : make_float2(0.0f, 0.0f);
    float a = 0.0f;
#pragma unroll
    for (int j = 0; j < JL2; j++) {
      float z  = bsw[j].x - sw.x;                              // s_bot - s_top
      float sp = fmaxf(z, 0.0f) + __logf(1.0f + __expf(-fabsf(z)));
      a += sp * bsw[j].y;
    }
    acc += a * sw.y;
  }
#pragma unroll
  for (int off = 32; off > 0; off >>= 1) acc += __shfl_down(acc, off);
  if ((tid & 63) == 0) red[tid >> 6] = acc;
  __syncthreads();
  if (tid == 0) {
    atomicAdd(&ws[S_SLOT(6, r)], red[0] + red[1] + red[2] + red[3]);
    __threadfence();
    int ticket = atomicAdd((int*)ws + SBASE + 7 * B, 1);
    isLast = (ticket == JC2 * B - 1) ? 1 : 0;
  }
  __syncthreads();

  if (isLast) {
    __threadfence();
    float lr = 0, lt = 0, ps = 0, ms = 0;
    if (tid < B) {
      float num = ws[S_SLOT(6, tid)];
      float den = ws[S_SLOT(0, tid)] * ws[S_SLOT(1, tid)] + 1e-8f;
      lr = num / den;
      lt = ws[S_SLOT(2, tid)] / (ws[S_SLOT(3, tid)] + 1e-8f);
      ps = ws[S_SLOT(4, tid)];
      ms = ws[S_SLOT(5, tid)];
    }
#pragma unroll
    for (int off = 16; off > 0; off >>= 1) {
      lr += __shfl_down(lr, off);
      lt += __shfl_down(lt, off);
      ps += __shfl_down(ps, off);
      ms += __shfl_down(ms, off);
    }
    if (tid == 0) {
      float avg_rank  = lr * (1.0f / B);
      float avg_trade = lt * (1.0f / B);
      out[0] = avg_rank + 0.25f * avg_trade;
      out[1] = avg_rank;
      out[2] = avg_trade;
      out[3] = ps / ms;
    }
  }
}

extern "C" void kernel_launch(void* const* d_in, const int* in_sizes, int n_in,
                              void* d_out, int out_size, void* d_ws, size_t ws_size,
                              hipStream_t stream) {
  const float* scores  = (const float*)d_in[0];
  const float* p_trade = (const float*)d_in[1];
  const float* y_rank  = (const float*)d_in[2];
  const float* y_trade = (const float*)d_in[3];
  const float* weights = (const float*)d_in[4];
  const unsigned char* mask = (const unsigned char*)d_in[5];
  float* out = (float*)d_out;
  float* ws  = (float*)d_ws;

  wpl_phase1<<<B, 1024, 0, stream>>>(scores, p_trade, y_rank, y_trade,
                                     weights, mask, ws);
  wpl_pair<<<dim3(JC2, B), 256, 0, stream>>>(ws, out);
}